// Round 5
// baseline (273.570 us; speedup 1.0000x reference)
//
#include <hip/hip_runtime.h>
#include <hip/hip_cooperative_groups.h>

namespace cg = cooperative_groups;

// out = SEQ*(X@Wv + bv)@Wo + bo   (reference's 'nhkq,nvhd->nvhd' einsum reduces the
// softmax weights over BOTH seq axes; each softmax row sums to 1 -> scalar SEQ per
// (n,h); Q/K/mask/softmax are dead code).
// WcT[n][i] = SEQ*sum_j Wo[j][n]*Wv[i][j]; cvec = SEQ*bv@Wo;
// out[m][n] = sum_i X[m][i]*WcT[n][i] + cvec[n] + bo[n].
// Split-bf16 MFMA (x = hi+lo; terms hH+hL+lH -> rel err ~2^-16; absmax budget 32).
// Round 5: single cooperative dispatch, phases P0(zero+transpose) / P1(WcT gemm) /
// P2(out gemm) separated by grid.sync(); issue-early/write-late staging in gemms.
// ws: WoTh (4MB) | WoTl (4MB) | WcT f32 (1MB) | cvec (2KB)  [WcT,cvec contiguous].

#define DM 512
#define HC 4096
#define SEQF 2048.0f
#define LDR 40  // LDS row stride in ushorts: 80B rows, 16B-aligned

typedef short bf16x8 __attribute__((ext_vector_type(8)));
typedef float f32x4 __attribute__((ext_vector_type(4)));

__device__ __forceinline__ void split2(float x, ushort& h, ushort& l) {
    unsigned b = __float_as_uint(x);
    h = (ushort)(b >> 16);
    float hf = __uint_as_float((unsigned)h << 16);
    l = (ushort)(__float_as_uint(x - hf) >> 16);
}
__device__ __forceinline__ float bf2f(ushort u) {
    return __uint_as_float((unsigned)u << 16);
}

__global__ __launch_bounds__(256) void fused_mha(
    const float* __restrict__ X, const float* __restrict__ Wv,
    const float* __restrict__ bv, const float* __restrict__ Wo,
    const float* __restrict__ bo, ushort* __restrict__ WoTh,
    ushort* __restrict__ WoTl, float* __restrict__ WcT,
    float* __restrict__ cvec, float* __restrict__ out) {
    __shared__ alignas(16) unsigned char smem[20480];
    ushort* Ah = (ushort*)smem;     // 2560 ushorts each
    ushort* Al = Ah + 2560;
    ushort* Bh = Al + 2560;
    ushort* Bl = Bh + 2560;

    const int bid = blockIdx.x, tid = threadIdx.x;
    const int lane = tid & 63, wave = tid >> 6;
    const int wm = wave * 16, fr = lane & 15, fs = (lane >> 4) * 8;
    const int r = tid >> 2, co = (tid & 3) * 8;  // gemm staging: 64 rows x 32 k

    // ================= P0a: zero WcT (512*512) + cvec (512) ==================
    {   // 513 dwords per block over the contiguous WcT|cvec region
        const int base = bid * 513;
        WcT[base + tid] = 0.f;
        WcT[base + 256 + tid] = 0.f;
        if (tid == 0) WcT[base + 512] = 0.f;
    }
    // ================= P0b: Wo[4096][512] -> WoT hi/lo [512][4096] ===========
    {
        float (*T)[65] = (float(*)[65])smem;
        const int bj = bid & 63, bn = bid >> 6;  // 64 j-tiles x 8 n-tiles
        const int rr = tid >> 2, c16 = (tid & 3) * 16;
        const float* p = Wo + (size_t)(bj * 64 + rr) * DM + bn * 64 + c16;
#pragma unroll
        for (int c = 0; c < 4; ++c) {
            float4 v = *reinterpret_cast<const float4*>(p + c * 4);
            T[rr][c16 + c * 4 + 0] = v.x;
            T[rr][c16 + c * 4 + 1] = v.y;
            T[rr][c16 + c * 4 + 2] = v.z;
            T[rr][c16 + c * 4 + 3] = v.w;
        }
        __syncthreads();
        const size_t off = (size_t)(bn * 64 + rr) * HC + bj * 64 + c16;
#pragma unroll
        for (int q = 0; q < 4; ++q) {
            ushort4 uh, ul;
            split2(T[c16 + q * 4 + 0][rr], uh.x, ul.x);
            split2(T[c16 + q * 4 + 1][rr], uh.y, ul.y);
            split2(T[c16 + q * 4 + 2][rr], uh.z, ul.z);
            split2(T[c16 + q * 4 + 3][rr], uh.w, ul.w);
            *reinterpret_cast<ushort4*>(&WoTh[off + q * 4]) = uh;
            *reinterpret_cast<ushort4*>(&WoTl[off + q * 4]) = ul;
        }
    }
    cg::this_grid().sync();

    // ================= P1: WcT[n][i] += SEQ * sum_k WoT[n][k]*Wv[i][k] =======
    {
        const int lin = (bid & 7) * 64 + (bid >> 3);  // XCD-grouped
        const int kc = lin >> 6, tile = lin & 63;
        const int nt = tile >> 3, it = tile & 7;
        const int a0 = nt * 64, b0 = it * 64, kb = kc * 512;
        const size_t aoff = (size_t)(a0 + r) * HC + co;
        const float* bp = Wv + (size_t)(b0 + r) * HC + co;

        int4 rah = *reinterpret_cast<const int4*>(&WoTh[aoff + kb]);
        int4 ral = *reinterpret_cast<const int4*>(&WoTl[aoff + kb]);
        float4 rb0 = *reinterpret_cast<const float4*>(bp + kb);
        float4 rb1 = *reinterpret_cast<const float4*>(bp + kb + 4);
        auto stash = [&]() {
            *reinterpret_cast<int4*>(&Ah[r * LDR + co]) = rah;
            *reinterpret_cast<int4*>(&Al[r * LDR + co]) = ral;
            ushort4 h0, l0, h1, l1;
            split2(rb0.x, h0.x, l0.x); split2(rb0.y, h0.y, l0.y);
            split2(rb0.z, h0.z, l0.z); split2(rb0.w, h0.w, l0.w);
            split2(rb1.x, h1.x, l1.x); split2(rb1.y, h1.y, l1.y);
            split2(rb1.z, h1.z, l1.z); split2(rb1.w, h1.w, l1.w);
            *reinterpret_cast<ushort4*>(&Bh[r * LDR + co])     = h0;
            *reinterpret_cast<ushort4*>(&Bh[r * LDR + co + 4]) = h1;
            *reinterpret_cast<ushort4*>(&Bl[r * LDR + co])     = l0;
            *reinterpret_cast<ushort4*>(&Bl[r * LDR + co + 4]) = l1;
        };
        stash();
        __syncthreads();
        f32x4 acc[4] = {};
        for (int t = 0; t < 16; ++t) {
            if (t < 15) {
                const int k1 = kb + (t + 1) * 32;
                rah = *reinterpret_cast<const int4*>(&WoTh[aoff + k1]);
                ral = *reinterpret_cast<const int4*>(&WoTl[aoff + k1]);
                rb0 = *reinterpret_cast<const float4*>(bp + k1);
                rb1 = *reinterpret_cast<const float4*>(bp + k1 + 4);
            }
            const int ai = (wm + fr) * LDR + fs;
            const bf16x8 ah = *reinterpret_cast<const bf16x8*>(&Ah[ai]);
            const bf16x8 al = *reinterpret_cast<const bf16x8*>(&Al[ai]);
#pragma unroll
            for (int g = 0; g < 4; ++g) {
                const int bi = (g * 16 + fr) * LDR + fs;
                const bf16x8 bh = *reinterpret_cast<const bf16x8*>(&Bh[bi]);
                const bf16x8 bl = *reinterpret_cast<const bf16x8*>(&Bl[bi]);
                acc[g] = __builtin_amdgcn_mfma_f32_16x16x32_bf16(ah, bh, acc[g], 0, 0, 0);
                acc[g] = __builtin_amdgcn_mfma_f32_16x16x32_bf16(ah, bl, acc[g], 0, 0, 0);
                acc[g] = __builtin_amdgcn_mfma_f32_16x16x32_bf16(al, bh, acc[g], 0, 0, 0);
            }
            __syncthreads();
            if (t < 15) stash();
            __syncthreads();
        }
#pragma unroll
        for (int g = 0; g < 4; ++g)
#pragma unroll
            for (int q = 0; q < 4; ++q) {
                const int row = a0 + wm + (lane >> 4) * 4 + q;   // n
                const int col = b0 + g * 16 + (lane & 15);       // i
                atomicAdd(&WcT[(size_t)row * DM + col], SEQF * acc[g][q]);
            }
        // cvec[n] += SEQ * sum_{j in this block's 64-wide j-slice} bv[j]*WoT[n][j]
        if (tid < 64) {
            const int jb = kb + it * 64;
            float s = 0.f;
#pragma unroll 8
            for (int jj = 0; jj < 64; ++jj) {
                const int j = jb + jj;
                const size_t o = (size_t)(a0 + tid) * HC + j;
                s = fmaf(bv[j], bf2f(WoTh[o]) + bf2f(WoTl[o]), s);
            }
            atomicAdd(&cvec[a0 + tid], SEQF * s);
        }
    }
    cg::this_grid().sync();

    // ================= P2: out[m][n] = sum_i X[m][i]*WcT[n][i] + cvec + bo ===
    {
        const int lin = (bid & 7) * 64 + (bid >> 3);  // XCD owns 8 m-tiles x all n
        const int mt = lin >> 3, nt = lin & 7;
        const int a0 = mt * 64, b0 = nt * 64;
        const float* ap = X + (size_t)(a0 + r) * DM + co;
        const float* bp = WcT + (size_t)(b0 + r) * DM + co;

        float4 ra0 = *reinterpret_cast<const float4*>(ap);
        float4 ra1 = *reinterpret_cast<const float4*>(ap + 4);
        float4 rb0 = *reinterpret_cast<const float4*>(bp);
        float4 rb1 = *reinterpret_cast<const float4*>(bp + 4);
        auto stash = [&]() {
            ushort4 h, l;
            split2(ra0.x, h.x, l.x); split2(ra0.y, h.y, l.y);
            split2(ra0.z, h.z, l.z); split2(ra0.w, h.w, l.w);
            *reinterpret_cast<ushort4*>(&Ah[r * LDR + co]) = h;
            *reinterpret_cast<ushort4*>(&Al[r * LDR + co]) = l;
            split2(ra1.x, h.x, l.x); split2(ra1.y, h.y, l.y);
            split2(ra1.z, h.z, l.z); split2(ra1.w, h.w, l.w);
            *reinterpret_cast<ushort4*>(&Ah[r * LDR + co + 4]) = h;
            *reinterpret_cast<ushort4*>(&Al[r * LDR + co + 4]) = l;
            split2(rb0.x, h.x, l.x); split2(rb0.y, h.y, l.y);
            split2(rb0.z, h.z, l.z); split2(rb0.w, h.w, l.w);
            *reinterpret_cast<ushort4*>(&Bh[r * LDR + co]) = h;
            *reinterpret_cast<ushort4*>(&Bl[r * LDR + co]) = l;
            split2(rb1.x, h.x, l.x); split2(rb1.y, h.y, l.y);
            split2(rb1.z, h.z, l.z); split2(rb1.w, h.w, l.w);
            *reinterpret_cast<ushort4*>(&Bh[r * LDR + co + 4]) = h;
            *reinterpret_cast<ushort4*>(&Bl[r * LDR + co + 4]) = l;
        };
        stash();
        __syncthreads();
        f32x4 acc[4] = {};
        for (int t = 0; t < 16; ++t) {
            if (t < 15) {
                const int k1 = (t + 1) * 32;
                ra0 = *reinterpret_cast<const float4*>(ap + k1);
                ra1 = *reinterpret_cast<const float4*>(ap + k1 + 4);
                rb0 = *reinterpret_cast<const float4*>(bp + k1);
                rb1 = *reinterpret_cast<const float4*>(bp + k1 + 4);
            }
            const int ai = (wm + fr) * LDR + fs;
            const bf16x8 ah = *reinterpret_cast<const bf16x8*>(&Ah[ai]);
            const bf16x8 al = *reinterpret_cast<const bf16x8*>(&Al[ai]);
#pragma unroll
            for (int g = 0; g < 4; ++g) {
                const int bi = (g * 16 + fr) * LDR + fs;
                const bf16x8 bh = *reinterpret_cast<const bf16x8*>(&Bh[bi]);
                const bf16x8 bl = *reinterpret_cast<const bf16x8*>(&Bl[bi]);
                acc[g] = __builtin_amdgcn_mfma_f32_16x16x32_bf16(ah, bh, acc[g], 0, 0, 0);
                acc[g] = __builtin_amdgcn_mfma_f32_16x16x32_bf16(ah, bl, acc[g], 0, 0, 0);
                acc[g] = __builtin_amdgcn_mfma_f32_16x16x32_bf16(al, bh, acc[g], 0, 0, 0);
            }
            __syncthreads();
            if (t < 15) stash();
            __syncthreads();
        }
#pragma unroll
        for (int g = 0; g < 4; ++g) {
            const int n = b0 + g * 16 + (lane & 15);
            const float cb = cvec[n] + bo[n];
#pragma unroll
            for (int q = 0; q < 4; ++q) {
                const int m = a0 + wm + (lane >> 4) * 4 + q;
                out[(size_t)m * DM + n] = acc[g][q] + cb;
            }
        }
    }
}

extern "C" void kernel_launch(void* const* d_in, const int* in_sizes, int n_in,
                              void* d_out, int out_size, void* d_ws, size_t ws_size,
                              hipStream_t stream) {
    // inputs: 0 input, 1 mask, 2 Wq, 3 bq, 4 Wk, 5 bk, 6 Wv, 7 bv, 8 Wo, 9 bo
    const float* X  = (const float*)d_in[0];
    const float* Wv = (const float*)d_in[6];
    const float* bv = (const float*)d_in[7];
    const float* Wo = (const float*)d_in[8];
    const float* bo = (const float*)d_in[9];
    float* out = (float*)d_out;

    ushort* WoTh = (ushort*)d_ws;                      // 4 MB
    ushort* WoTl = WoTh + (size_t)DM * HC;             // 4 MB
    float*  WcT  = (float*)(WoTl + (size_t)DM * HC);   // 1 MB fp32
    float*  cvec = WcT + (size_t)DM * DM;              // 2 KB (contiguous after WcT)

    void* args[] = {(void*)&X, (void*)&Wv, (void*)&bv, (void*)&Wo, (void*)&bo,
                    (void*)&WoTh, (void*)&WoTl, (void*)&WcT, (void*)&cvec, (void*)&out};
    hipLaunchCooperativeKernel(fused_mha, dim3(512), dim3(256), args, 0, stream);
}

// Round 6
// 158.141 us; speedup vs baseline: 1.7299x; 1.7299x over previous
//
#include <hip/hip_runtime.h>

// out = SEQ*(X@Wv + bv)@Wo + bo   (reference's 'nhkq,nvhd->nvhd' einsum reduces the
// softmax weights over BOTH seq axes; each softmax row sums to 1 -> scalar SEQ per
// (n,h); Q/K/mask/softmax are dead code).
// WcT[n][i] = SEQ*sum_j Wo[j][n]*Wv[i][j]; cvec = SEQ*bv@Wo;
// out[m][n] = sum_i X[m][i]*WcT[n][i] + cvec[n] + bo[n].
// Split-bf16 MFMA (x = hi+lo; terms hH+hL+lH -> rel err ~2^-16; absmax budget 32).
// Round 6: round-4 structure (separate small kernels, single-buffered LDS), but
// Wo-transpose folded into gemm_wcT staging (kills prep_wo dispatch + 16 MB
// round-trip) and cvec folded into gemm_wcT's it==7 blocks. 3 dispatches total.
// ws: WcT f32 (1MB) | cvec (2KB).

#define DM 512
#define HC 4096
#define SEQF 2048.0f
#define LDR 40  // LDS row stride in ushorts: 80B rows, 16B-aligned

typedef short bf16x8 __attribute__((ext_vector_type(8)));
typedef float f32x4 __attribute__((ext_vector_type(4)));

__device__ __forceinline__ void split2(float x, ushort& h, ushort& l) {
    unsigned b = __float_as_uint(x);
    h = (ushort)(b >> 16);
    float hf = __uint_as_float((unsigned)h << 16);
    l = (ushort)(__float_as_uint(x - hf) >> 16);
}

// stage 64 rows x 32 k: fp32 global (K-contiguous rows) -> split bf16 hi/lo LDS
__device__ __forceinline__ void stage64_f32(const float* __restrict__ src, int ld,
                                            int row0, int k0, ushort* Hh, ushort* Hl,
                                            int tid) {
    const int r = tid >> 2, co = (tid & 3) * 8;
    const float* p = src + (size_t)(row0 + r) * ld + k0 + co;
    const float4 v0 = *reinterpret_cast<const float4*>(p);
    const float4 v1 = *reinterpret_cast<const float4*>(p + 4);
    ushort4 h0, l0, h1, l1;
    split2(v0.x, h0.x, l0.x); split2(v0.y, h0.y, l0.y);
    split2(v0.z, h0.z, l0.z); split2(v0.w, h0.w, l0.w);
    split2(v1.x, h1.x, l1.x); split2(v1.y, h1.y, l1.y);
    split2(v1.z, h1.z, l1.z); split2(v1.w, h1.w, l1.w);
    *reinterpret_cast<ushort4*>(&Hh[r * LDR + co])     = h0;
    *reinterpret_cast<ushort4*>(&Hh[r * LDR + co + 4]) = h1;
    *reinterpret_cast<ushort4*>(&Hl[r * LDR + co])     = l0;
    *reinterpret_cast<ushort4*>(&Hl[r * LDR + co + 4]) = l1;
}

// ---- gemm_wcT: WcT[n][i] += SEQ * sum_j Wo[j][n]*Wv[i][j] ----
// A = Wo^T staged by in-kernel transpose (Wo rows coalesced, LDS scatter-write);
// B = Wv split on the fly. 64x64 tile, 4 waves, BK=32, split-K 8 -> 512 blocks.
// it==7 blocks also accumulate cvec partials from L2-warm Wo.
__global__ __launch_bounds__(256) void gemm_wcT(const float* __restrict__ Wo,
                                                const float* __restrict__ Wv,
                                                const float* __restrict__ bv,
                                                float* __restrict__ WcT,
                                                float* __restrict__ cvec) {
    __shared__ ushort Ah[64 * LDR], Al[64 * LDR], Bh[64 * LDR], Bl[64 * LDR];
    const int d = blockIdx.x;                  // 0..511
    const int lin = (d & 7) * 64 + (d >> 3);   // bijective; one XCD = one k-chunk
    const int kc = lin >> 6, tile = lin & 63;
    const int nt = tile >> 3, it = tile & 7;
    const int a0 = nt * 64, b0 = it * 64, kb = kc * 512;
    const int tid = threadIdx.x, wave = tid >> 6, lane = tid & 63;
    const int wm = wave * 16, fr = lane & 15, fs = (lane >> 4) * 8;
    const int jr = tid >> 3, nc = (tid & 7) * 8;  // A-transpose staging coords

    f32x4 acc[4] = {};
    for (int t = 0; t < 16; ++t) {
        const int k0 = kb + t * 32;
        // A: Wo[k0..k0+32][a0..a0+64] -> Ah/Al[n][j] (transposed, split)
        {
            const float* p = Wo + (size_t)(k0 + jr) * DM + a0 + nc;
            const float4 v0 = *reinterpret_cast<const float4*>(p);
            const float4 v1 = *reinterpret_cast<const float4*>(p + 4);
            const float w[8] = {v0.x, v0.y, v0.z, v0.w, v1.x, v1.y, v1.z, v1.w};
#pragma unroll
            for (int q = 0; q < 8; ++q) {
                ushort h, l;
                split2(w[q], h, l);
                Ah[(nc + q) * LDR + jr] = h;
                Al[(nc + q) * LDR + jr] = l;
            }
        }
        // B: Wv[b0..b0+64][k0..k0+32] (K-contiguous) split
        stage64_f32(Wv, HC, b0, k0, Bh, Bl, tid);
        __syncthreads();
        const int ai = (wm + fr) * LDR + fs;
        const bf16x8 ah = *reinterpret_cast<const bf16x8*>(&Ah[ai]);
        const bf16x8 al = *reinterpret_cast<const bf16x8*>(&Al[ai]);
#pragma unroll
        for (int g = 0; g < 4; ++g) {
            const int bi = (g * 16 + fr) * LDR + fs;
            const bf16x8 bh = *reinterpret_cast<const bf16x8*>(&Bh[bi]);
            const bf16x8 bl = *reinterpret_cast<const bf16x8*>(&Bl[bi]);
            acc[g] = __builtin_amdgcn_mfma_f32_16x16x32_bf16(ah, bh, acc[g], 0, 0, 0);
            acc[g] = __builtin_amdgcn_mfma_f32_16x16x32_bf16(ah, bl, acc[g], 0, 0, 0);
            acc[g] = __builtin_amdgcn_mfma_f32_16x16x32_bf16(al, bh, acc[g], 0, 0, 0);
        }
        __syncthreads();
    }
#pragma unroll
    for (int g = 0; g < 4; ++g)
#pragma unroll
        for (int q = 0; q < 4; ++q) {
            const int row = a0 + wm + (lane >> 4) * 4 + q;   // n
            const int col = b0 + g * 16 + (lane & 15);       // i
            atomicAdd(&WcT[(size_t)row * DM + col], SEQF * acc[g][q]);
        }
    // cvec[n] += SEQ * sum_{j in kb..kb+512} bv[j]*Wo[j][n]  (it==7: 64 blocks)
    if (it == 7) {
        const int n = a0 + (tid & 63);
        const int jseg = kb + (tid >> 6) * 128;
        float s = 0.f;
#pragma unroll 8
        for (int jj = 0; jj < 128; ++jj)
            s = fmaf(bv[jseg + jj], Wo[(size_t)(jseg + jj) * DM + n], s);
        atomicAdd(&cvec[n], SEQF * s);
    }
}

// ---- gemm_out: out[m][n] = sum_i X[m][i]*WcT[n][i] + cvec[n] + bo[n] ----
// 64x64 tile, K=512 (16 steps), grid 512 = 64 mt x 8 nt; WcT split on the fly.
__global__ __launch_bounds__(256) void gemm_out(const float* __restrict__ X,
                                                const float* __restrict__ WcT,
                                                const float* __restrict__ cvec,
                                                const float* __restrict__ bo,
                                                float* __restrict__ out) {
    __shared__ ushort Ah[64 * LDR], Al[64 * LDR], Bh[64 * LDR], Bl[64 * LDR];
    const int d = blockIdx.x;                  // 0..511
    const int lin = (d & 7) * 64 + (d >> 3);   // XCD owns 8 m-tiles x all n
    const int mt = lin >> 3, nt = lin & 7;
    const int a0 = mt * 64, b0 = nt * 64;
    const int tid = threadIdx.x, wave = tid >> 6, lane = tid & 63;
    const int wm = wave * 16, fr = lane & 15, fs = (lane >> 4) * 8;

    f32x4 acc[4] = {};
    for (int t = 0; t < 16; ++t) {
        const int k0 = t * 32;
        stage64_f32(X, DM, a0, k0, Ah, Al, tid);
        stage64_f32(WcT, DM, b0, k0, Bh, Bl, tid);
        __syncthreads();
        const int ai = (wm + fr) * LDR + fs;
        const bf16x8 ah = *reinterpret_cast<const bf16x8*>(&Ah[ai]);
        const bf16x8 al = *reinterpret_cast<const bf16x8*>(&Al[ai]);
#pragma unroll
        for (int g = 0; g < 4; ++g) {
            const int bi = (g * 16 + fr) * LDR + fs;
            const bf16x8 bh = *reinterpret_cast<const bf16x8*>(&Bh[bi]);
            const bf16x8 bl = *reinterpret_cast<const bf16x8*>(&Bl[bi]);
            acc[g] = __builtin_amdgcn_mfma_f32_16x16x32_bf16(ah, bh, acc[g], 0, 0, 0);
            acc[g] = __builtin_amdgcn_mfma_f32_16x16x32_bf16(ah, bl, acc[g], 0, 0, 0);
            acc[g] = __builtin_amdgcn_mfma_f32_16x16x32_bf16(al, bh, acc[g], 0, 0, 0);
        }
        __syncthreads();
    }
#pragma unroll
    for (int g = 0; g < 4; ++g) {
        const int n = b0 + g * 16 + (lane & 15);
        const float cb = cvec[n] + bo[n];
#pragma unroll
        for (int q = 0; q < 4; ++q) {
            const int m = a0 + wm + (lane >> 4) * 4 + q;
            out[(size_t)m * DM + n] = acc[g][q] + cb;
        }
    }
}

extern "C" void kernel_launch(void* const* d_in, const int* in_sizes, int n_in,
                              void* d_out, int out_size, void* d_ws, size_t ws_size,
                              hipStream_t stream) {
    // inputs: 0 input, 1 mask, 2 Wq, 3 bq, 4 Wk, 5 bk, 6 Wv, 7 bv, 8 Wo, 9 bo
    const float* X  = (const float*)d_in[0];
    const float* Wv = (const float*)d_in[6];
    const float* bv = (const float*)d_in[7];
    const float* Wo = (const float*)d_in[8];
    const float* bo = (const float*)d_in[9];
    float* out = (float*)d_out;

    float* WcT  = (float*)d_ws;                 // 1 MB fp32
    float* cvec = WcT + (size_t)DM * DM;        // 2 KB (contiguous after WcT)

    hipMemsetAsync(WcT, 0, (size_t)DM * DM * 4 + DM * 4, stream);  // WcT + cvec

    gemm_wcT<<<512, 256, 0, stream>>>(Wo, Wv, bv, WcT, cvec);
    gemm_out<<<512, 256, 0, stream>>>(X, WcT, cvec, bo, out);
}